// Round 8
// baseline (217.076 us; speedup 1.0000x reference)
//
#include <hip/hip_runtime.h>
#include <hip/hip_bf16.h>
#include <stdint.h>

typedef __hip_bfloat16 bf16;
typedef __attribute__((ext_vector_type(8))) short short8;   // 8 bf16 = 4 VGPRs
typedef __attribute__((ext_vector_type(4))) float floatx4;  // MFMA C/D frag

#define M_DIM 4096
#define H_DIM 1024
#define LDS_BUF 24576       // one stage: A 8KB + B 16KB (2 stages = 48 KB)
#define PHOFF 4194304u      // phase-1 source offset: +8192 chunks * 512 elems

// fp32 -> bf16 bits, round-to-nearest-even (inputs are finite)
__device__ __forceinline__ unsigned short f2bf(float f) {
    uint32_t u = __float_as_uint(f);
    uint32_t r = (u + 0x7FFFu + ((u >> 16) & 1u)) >> 16;
    return (unsigned short)r;
}

__device__ __forceinline__ float fast_sigmoid(float v) {
    return 1.0f / (1.0f + __expf(-v));
}
__device__ __forceinline__ float fast_tanh(float v) {
    return 2.0f / (1.0f + __expf(-2.0f * v)) - 1.0f;
}

// ---------------------------------------------------------------------------
// Kernel 1: PACK fp32 -> bf16 chunks in swizzled LDS-image order (unchanged R7).
// chunk = 1 KB = [16 rows][4 k-slots][8 bf16], slot = kgroup ^ ((row>>1)&3).
// ws chunk map (512 bf16 each, 32768 chunks = 32 MB):
//   [0,8192):      x  chunks, W = mx*256 + kt*8 + ch
//   [8192,16384):  h  chunks, same decode
//   [16384,24576): Wx chunks, W-16384 = (ny*16+g*4+b4)*32 + kt
//   [24576,32768): Wh chunks, same decode
__global__ __launch_bounds__(256)
void pack_bf16(const float* __restrict__ x, const float* __restrict__ h,
               const float* Wxf, const float* Wxi, const float* Wxo, const float* Wxc,
               const float* Whf, const float* Whi, const float* Who, const float* Whc,
               unsigned short* __restrict__ ws)
{
    const int w = threadIdx.x >> 6;
    const int l = threadIdx.x & 63;
    const uint32_t W = blockIdx.x * 4u + (uint32_t)w;   // chunk id [0, 32768)

    const uint32_t r  = (uint32_t)l >> 2;                       // row in chunk [0,16)
    const uint32_t kg = ((uint32_t)l & 3u) ^ ((r >> 1) & 3u);   // global k-group of slot

    const float* src;
    uint32_t row, kt;
    if (W < 16384u) {                    // A-chunks (x / h)
        const uint32_t Wa = W & 8191u;
        const uint32_t ch = Wa & 7u;
        kt = (Wa >> 3) & 31u;
        const uint32_t mx = Wa >> 8;
        src = (W < 8192u) ? x : h;
        row = mx * 128u + ch * 16u + r;
    } else {                             // B-chunks (Wx_g / Wh_g)
        const uint32_t V = W & 8191u;
        kt = V & 31u;
        uint32_t U = V >> 5;
        const uint32_t b4 = U & 3u;
        const uint32_t g  = (U >> 2) & 3u;
        const uint32_t ny = U >> 4;
        if (W < 24576u)
            src = (g == 0) ? Wxf : (g == 1) ? Wxi : (g == 2) ? Wxo : Wxc;
        else
            src = (g == 0) ? Whf : (g == 1) ? Whi : (g == 2) ? Who : Whc;
        row = ny * 64u + b4 * 16u + r;
    }
    const float* s = src + (size_t)row * 1024u + kt * 32u + kg * 8u;
    const float4 v0 = *(const float4*)s;
    const float4 v1 = *(const float4*)(s + 4);
    short8 pk;
    pk[0] = (short)f2bf(v0.x); pk[1] = (short)f2bf(v0.y);
    pk[2] = (short)f2bf(v0.z); pk[3] = (short)f2bf(v0.w);
    pk[4] = (short)f2bf(v1.x); pk[5] = (short)f2bf(v1.y);
    pk[6] = (short)f2bf(v1.z); pk[7] = (short)f2bf(v1.w);
    *(short8*)(ws + (size_t)W * 512u + (uint32_t)l * 8u) = pk;
}

// ---------------------------------------------------------------------------
// Kernel 2: fused 4-gate GEMM + LSTM pointwise — REGISTER staging (no
// global_load_lds: that path measured ~50 cyc/instr = the R2..R7 wall).
// Block: 512 threads (8 waves). Tile: 128 batch x 64 hidden x 4 gates.
// 2-stage LDS (48 KB) + 2 register chunk-buffers (depth-1 prefetch).
// Per iter kt (ONE s_barrier, no vmcnt drain):
//   barrier(lgkmcnt 0)                        [buf[kt&1] writes visible; WAR done]
//   load  G(kt+2) -> R[kt&1]                  [3x global_load_dwordx4]
//   ds_write R[(kt+1)&1] (=G(kt+1)) -> buf[(kt+1)&1]  [compiler emits vmcnt(3)]
//   compute(kt) from buf[kt&1]                [8 ds_read_b128 + 16 MFMA]
__global__ __launch_bounds__(512, 4)
void lstm_fused_kernel(const unsigned short* __restrict__ ws,
                       const float* __restrict__ c,
                       const float* __restrict__ bxf, const float* __restrict__ bhf,
                       const float* __restrict__ bxi, const float* __restrict__ bhi,
                       const float* __restrict__ bxo, const float* __restrict__ bho,
                       const float* __restrict__ bxc, const float* __restrict__ bhc,
                       float* __restrict__ out)
{
    __shared__ __align__(16) char lds[2 * LDS_BUF];

    const int tid  = threadIdx.x;
    const int w    = tid >> 6;     // 0..7
    const int lane = tid & 63;

    // XCD-aware block swizzle (1D grid of 512)
    const int bid = blockIdx.x;
    const int mx  = bid >> 4;                              // [0,32)
    const int ny  = ((bid & 7) << 1) | ((bid >> 3) & 1);   // [0,16)
    const int bm0 = mx * 128;
    const int bn0 = ny * 64;

    // staging: 24 packed chunks of 1 KB; wave w handles ch = w*3+i.
    // Phase-1 source = phase-0 + PHOFF (h after x; Wh after Wx — both +8192 chunks).
    const unsigned short* srcP[3];
    uint32_t kstr[3];
    uint32_t loffL[3];   // LDS byte offset within a stage (incl. lane*16)
#pragma unroll
    for (int i = 0; i < 3; ++i) {
        const int ch = w * 3 + i;
        if (ch < 8) {
            const uint32_t base = ((uint32_t)mx * 256u + (uint32_t)ch) * 512u;
            srcP[i] = ws + base + (uint32_t)lane * 8u;
            kstr[i] = 8u * 512u;
            loffL[i] = (uint32_t)ch * 1024u + (uint32_t)lane * 16u;
        } else {
            const int b  = ch - 8;
            const uint32_t g  = (uint32_t)b >> 2;
            const uint32_t b4 = (uint32_t)b & 3u;
            const uint32_t base = (16384u + ((uint32_t)ny * 16u + g * 4u + b4) * 32u) * 512u;
            srcP[i] = ws + base + (uint32_t)lane * 8u;
            kstr[i] = 512u;
            loffL[i] = 8192u + (uint32_t)b * 1024u + (uint32_t)lane * 16u;
        }
    }

    const int wrow  = (w & 1) * 64;    // 4 m-tiles
    const int wcol  = (w >> 1) * 16;   // one 16-col group within each gate
    const int lrc   = lane & 15;       // frag row (A) / col (B)
    const int lquad = lane >> 4;       // frag k-group (x8 elements)

    // reader-side swizzle (pack wrote this image): slot = lquad^((r>>1)&3)
    const uint32_t kslot = (((uint32_t)lquad ^ (((uint32_t)lrc >> 1) & 3u))) * 8u;

    uint32_t aoff[4];
#pragma unroll
    for (int mt = 0; mt < 4; ++mt)
        aoff[mt] = (uint32_t)((wrow + mt * 16 + lrc) * 32) + kslot;
    uint32_t boff[4];
#pragma unroll
    for (int g = 0; g < 4; ++g)
        boff[g] = (uint32_t)(g * 2048 + (wcol + lrc) * 32) + kslot;

    floatx4 acc[4][4];   // [gate][m-tile] = 64 fp32/lane
#pragma unroll
    for (int g = 0; g < 4; ++g)
#pragma unroll
        for (int mt = 0; mt < 4; ++mt)
            acc[g][mt] = (floatx4){0.f, 0.f, 0.f, 0.f};

    short8 R0[3], R1[3];   // register chunk-buffers (12 VGPRs each)

    auto load_chunks = [&](int kl, short8 (&R)[3]) {
        const uint32_t off = ((kl >= 32) ? PHOFF : 0u);
        const uint32_t kk = (uint32_t)(kl & 31);
#pragma unroll
        for (int i = 0; i < 3; ++i)
            R[i] = *(const short8*)(srcP[i] + off + kk * kstr[i]);
    };
    auto write_chunks = [&](short8 (&R)[3], uint32_t stage) {
        char* base = lds + stage * LDS_BUF;
#pragma unroll
        for (int i = 0; i < 3; ++i)
            *(short8*)(base + loffL[i]) = R[i];
    };
    auto compute = [&](uint32_t stage) {
        const char* base = lds + stage * LDS_BUF;
        const bf16* lA = (const bf16*)base;
        const bf16* lB = (const bf16*)(base + 8192);
        short8 afr[4];
#pragma unroll
        for (int mt = 0; mt < 4; ++mt)
            afr[mt] = *(const short8*)(lA + aoff[mt]);
#pragma unroll
        for (int g = 0; g < 4; ++g) {
            const short8 bfr = *(const short8*)(lB + boff[g]);
#pragma unroll
            for (int mt = 0; mt < 4; ++mt)
                acc[g][mt] = __builtin_amdgcn_mfma_f32_16x16x32_bf16(
                    afr[mt], bfr, acc[g][mt], 0, 0, 0);
        }
    };

    // prologue: G0->R0, G1->R1, stage G0 into buf0
    load_chunks(0, R0);
    load_chunks(1, R1);
    write_chunks(R0, 0);   // compiler waits the R0 loads precisely

    // pair-unrolled steady loop: iters 0..61 (stage indices compile-time)
    for (int kt = 0; kt < 62; kt += 2) {
        // even iter kt: compute buf0, write buf1, load -> R0
        asm volatile("s_waitcnt lgkmcnt(0)\ns_barrier" ::: "memory");
        load_chunks(kt + 2, R0);
        write_chunks(R1, 1);
        compute(0);
        // odd iter kt+1: compute buf1, write buf0, load -> R1
        asm volatile("s_waitcnt lgkmcnt(0)\ns_barrier" ::: "memory");
        load_chunks(kt + 3, R1);
        write_chunks(R0, 0);
        compute(1);
    }
    // iter 62: compute buf0, write G63 (in R1) -> buf1
    asm volatile("s_waitcnt lgkmcnt(0)\ns_barrier" ::: "memory");
    write_chunks(R1, 1);
    compute(0);
    // iter 63: compute buf1
    asm volatile("s_waitcnt lgkmcnt(0)\ns_barrier" ::: "memory");
    compute(1);

    // epilogue.  C/D layout: col = lane&15, row = (lane>>4)*4 + reg
    float* out_ct = out;
    float* out_ht = out + (size_t)M_DIM * H_DIM;
    {
        const int col = bn0 + wcol + lrc;
        const float bf_ = bxf[col] + bhf[col];
        const float bi_ = bxi[col] + bhi[col];
        const float bo_ = bxo[col] + bho[col];
        const float bc_ = bxc[col] + bhc[col];
#pragma unroll
        for (int mt = 0; mt < 4; ++mt) {
#pragma unroll
            for (int r = 0; r < 4; ++r) {
                const int row = bm0 + wrow + mt * 16 + lquad * 4 + r;
                const float gf = acc[0][mt][r] + bf_;
                const float gi = acc[1][mt][r] + bi_;
                const float go = acc[2][mt][r] + bo_;
                const float gc = acc[3][mt][r] + bc_;
                const float f    = fast_sigmoid(gf);
                const float ii   = fast_sigmoid(gi);
                const float o    = fast_sigmoid(go);
                const float ctil = fast_tanh(gc);
                const float cv   = c[(size_t)row * H_DIM + col];
                const float ctn  = f * cv + ctil * ii;
                const float htn  = fast_tanh(ctn) * o;
                out_ct[(size_t)row * H_DIM + col] = ctn;
                out_ht[(size_t)row * H_DIM + col] = htn;
            }
        }
    }
}

extern "C" void kernel_launch(void* const* d_in, const int* in_sizes, int n_in,
                              void* d_out, int out_size, void* d_ws, size_t ws_size,
                              hipStream_t stream) {
    (void)in_sizes; (void)n_in; (void)out_size; (void)ws_size;
    const float* x   = (const float*)d_in[0];
    const float* c   = (const float*)d_in[1];
    const float* h   = (const float*)d_in[2];
    const float* Wxf = (const float*)d_in[3];  const float* bxf = (const float*)d_in[4];
    const float* Whf = (const float*)d_in[5];  const float* bhf = (const float*)d_in[6];
    const float* Wxi = (const float*)d_in[7];  const float* bxi = (const float*)d_in[8];
    const float* Whi = (const float*)d_in[9];  const float* bhi = (const float*)d_in[10];
    const float* Wxo = (const float*)d_in[11]; const float* bxo = (const float*)d_in[12];
    const float* Who = (const float*)d_in[13]; const float* bho = (const float*)d_in[14];
    const float* Wxc = (const float*)d_in[15]; const float* bxc = (const float*)d_in[16];
    const float* Whc = (const float*)d_in[17]; const float* bhc = (const float*)d_in[18];
    float* out = (float*)d_out;
    unsigned short* ws = (unsigned short*)d_ws;   // 32768 chunks x 1 KB = 32 MB

    pack_bf16<<<8192, 256, 0, stream>>>(x, h,
        Wxf, Wxi, Wxo, Wxc, Whf, Whi, Who, Whc, ws);

    lstm_fused_kernel<<<512, 512, 0, stream>>>(ws, c,
        bxf, bhf, bxi, bhi, bxo, bho, bxc, bhc, out);
}